// Round 1
// 290.544 us; speedup vs baseline: 1.2404x; 1.2404x over previous
//
#include <hip/hip_runtime.h>
#include <hip/hip_bf16.h>

typedef short s16x8 __attribute__((ext_vector_type(8)));
typedef float f32x4 __attribute__((ext_vector_type(4)));

namespace {
constexpr int kB   = 8;
constexpr int kN   = 5000;
constexpr int kE   = 40000;
constexpr int kF   = 64;
constexpr int kFE  = 16;
constexpr int kFil = 96;
constexpr float kEps = 1e-3f;
constexpr int kBN = kB * kN;   // 40000
constexpr int kBE = kB * kE;   // 320000
constexpr int kKp = 160;       // padded K (msg 144->160, upd exact 160)
constexpr int kLd = 168;       // LDS row stride in bf16 elems (bank decorrelation)
constexpr int kBM = 128;       // rows per block
}

// float -> bf16 (RNE) bit-twiddle — kept only for the tiny prep kernel
__device__ inline unsigned short f2bf(float x) {
    unsigned u = __float_as_uint(x);
    u += 0x7FFFu + ((u >> 16) & 1u);
    return (unsigned short)(u >> 16);
}

// 8x fp32 -> 8x bf16 via v_cvt_pk_bf16_f32 (compiler-emitted, RNE — bitwise
// identical to the old bit-twiddle but 1 inst per 2 values instead of ~4/value)
__device__ inline s16x8 pack8(const float4& a, const float4& b) {
    union { s16x8 s; __hip_bfloat162 h[4]; } r;
    r.h[0] = __float22bfloat162_rn(make_float2(a.x, a.y));
    r.h[1] = __float22bfloat162_rn(make_float2(a.z, a.w));
    r.h[2] = __float22bfloat162_rn(make_float2(b.x, b.y));
    r.h[3] = __float22bfloat162_rn(make_float2(b.z, b.w));
    return r.s;
}

// ---------------------------------------------------------------------------
// Prep: W (K,96) fp32 -> WT (96,Kp) bf16, zero-padded K rows. Runs once/call.
// ---------------------------------------------------------------------------
__global__ void prep_wT(const float* __restrict__ Wm, const float* __restrict__ Wu,
                        short* __restrict__ wmT, short* __restrict__ wuT) {
    const int t = blockIdx.x * 256 + threadIdx.x;
    if (t >= 96 * kKp) return;
    const int n = t / kKp, k = t % kKp;
    wmT[t] = (k < 144) ? (short)f2bf(Wm[(size_t)k * 96 + n]) : (short)0;
    wuT[t] = (short)f2bf(Wu[(size_t)k * 96 + n]);
}

// ---------------------------------------------------------------------------
// Shared MFMA GEMM (128xKp @ Kpx96) + fp32 bias/ReLU/LN epilogue + store.
// A-frag: A[m=lane&15][k=quad*8+j]; B-frag: B[k=quad*8+j][n=lane&15];
// C/D: col=lane&15, row=quad*4+reg  [per guide §3, HW-verified mappings].
// LN: row lives in one 16-lane quad across 6 N-tiles -> shfl_xor(1,2,4,8).
// NEW: optional fused aggregation — when aggOut != nullptr, each finished
// row (an edge's LN'd message) is also atomicAdd'ed into agg[b,dst].
// Fire-and-forget global_atomic_add_f32 (unsafeAtomicAdd): no wave stall.
// ---------------------------------------------------------------------------
__device__ inline void gemm_ln_store(const short* sX, const short* sB,
                                     const float* __restrict__ bias,
                                     const float* __restrict__ gamma_,
                                     const float* __restrict__ beta_,
                                     float* __restrict__ out,
                                     const int* __restrict__ edges2,  // msg only
                                     float* __restrict__ aggOut,      // msg only
                                     int rowBase, int rowMax) {
    const int tid  = threadIdx.x;
    const int w    = tid >> 6;
    const int lane = tid & 63;
    const int cl   = lane & 15;
    const int quad = lane >> 4;

    f32x4 acc[6] = {};
    const short* aBase = sX + (16 * w + cl) * kLd + quad * 8;
#pragma unroll
    for (int ks = 0; ks < 5; ++ks) {
        s16x8 a = *reinterpret_cast<const s16x8*>(aBase + ks * 32);
#pragma unroll
        for (int t = 0; t < 6; ++t) {
            s16x8 b = *reinterpret_cast<const s16x8*>(
                sB + (16 * t + cl) * kLd + ks * 32 + quad * 8);
            acc[t] = __builtin_amdgcn_mfma_f32_16x16x32_bf16(a, b, acc[t], 0, 0, 0);
        }
    }

    float bmv[6], gv[6], bv[6];
#pragma unroll
    for (int t = 0; t < 6; ++t) {
        const int c = 16 * t + cl;
        bmv[t] = bias[c]; gv[t] = gamma_[c]; bv[t] = beta_[c];
    }
#pragma unroll
    for (int j = 0; j < 4; ++j) {
        float v0[6];
        float s = 0.f;
#pragma unroll
        for (int t = 0; t < 6; ++t) {
            v0[t] = fmaxf(acc[t][j] + bmv[t], 0.f);
            s += v0[t];
        }
        s += __shfl_xor(s, 1); s += __shfl_xor(s, 2);
        s += __shfl_xor(s, 4); s += __shfl_xor(s, 8);
        const float mu = s * (1.f / 96.f);
        float q = 0.f;
#pragma unroll
        for (int t = 0; t < 6; ++t) {
            const float d = v0[t] - mu;
            q = fmaf(d, d, q);
        }
        q += __shfl_xor(q, 1); q += __shfl_xor(q, 2);
        q += __shfl_xor(q, 4); q += __shfl_xor(q, 8);
        const float inv = rsqrtf(q * (1.f / 96.f) + kEps);
        const int row = rowBase + 16 * w + 4 * quad + j;
        if (row < rowMax) {
            float ov[6];
#pragma unroll
            for (int t = 0; t < 6; ++t)
                ov[t] = (v0[t] - mu) * inv * gv[t] + bv[t];
            float* orow = out + (size_t)row * kFil;
#pragma unroll
            for (int t = 0; t < 6; ++t)
                orow[16 * t + cl] = ov[t];
            if (aggOut) {
                const int b  = row / kE;                     // magic-mul div
                const int dn = edges2[(size_t)row * 2 + 1];  // L2-hot (staged it)
                float* arow = aggOut + ((size_t)b * kN + dn) * kFil;
#pragma unroll
                for (int t = 0; t < 6; ++t)
                    unsafeAtomicAdd(&arow[16 * t + cl], ov[t]);
            }
        }
    }
}

// ---------------------------------------------------------------------------
// Message layer (MFMA): block = 128 edges. Threads 0..255 gather/stage X rows
// [src(64)|dst(64)|efeat(16)|zeros(16)] as bf16; threads 256..511 stage WT.
// Epilogue fuses segment-sum via atomics into agg — no CSR, no re-read.
// ---------------------------------------------------------------------------
__global__ __launch_bounds__(512) void msg_mfma(
    const float* __restrict__ nodes, const float* __restrict__ efeat,
    const int* __restrict__ edges, const short* __restrict__ wmT,
    const float* __restrict__ bm, const float* __restrict__ g,
    const float* __restrict__ be, float* __restrict__ out_msg,
    float* __restrict__ agg) {
    __shared__ short sX[kBM * kLd];   // 43008 B
    __shared__ short sB[96 * kLd];    // 32256 B
    const int tid = threadIdx.x;
    if (tid < 256) {
        const int r = tid >> 1, half = tid & 1;
        const int edge = blockIdx.x * kBM + r;     // 2500*128 = 320000 exact
        const int b = edge / kE;
        short* dstRow = sX + r * kLd;
        if (half == 0) {
            const int s = edges[(size_t)edge * 2];
            const float4* p = reinterpret_cast<const float4*>(
                nodes + ((size_t)b * kN + s) * kF);
#pragma unroll
            for (int c = 0; c < 8; ++c)
                *reinterpret_cast<s16x8*>(dstRow + 8 * c) = pack8(p[2 * c], p[2 * c + 1]);
        } else {
            const int d = edges[(size_t)edge * 2 + 1];
            const float4* p = reinterpret_cast<const float4*>(
                nodes + ((size_t)b * kN + d) * kF);
#pragma unroll
            for (int c = 0; c < 8; ++c)
                *reinterpret_cast<s16x8*>(dstRow + 64 + 8 * c) = pack8(p[2 * c], p[2 * c + 1]);
            const float4* pe = reinterpret_cast<const float4*>(efeat + (size_t)edge * kFE);
#pragma unroll
            for (int c = 0; c < 2; ++c)
                *reinterpret_cast<s16x8*>(dstRow + 128 + 8 * c) = pack8(pe[2 * c], pe[2 * c + 1]);
            s16x8 z = {};
            *reinterpret_cast<s16x8*>(dstRow + 144) = z;   // zero-pad K 144..159
            *reinterpret_cast<s16x8*>(dstRow + 152) = z;
        }
    } else {
        for (int i = tid - 256; i < 96 * kKp / 8; i += 256) {   // 1920 16B chunks
            const int n = i / 20, c = i % 20;
            *reinterpret_cast<s16x8*>(sB + n * kLd + 8 * c) =
                *reinterpret_cast<const s16x8*>(wmT + n * kKp + 8 * c);
        }
    }
    __syncthreads();
    gemm_ln_store(sX, sB, bm, g, be, out_msg, edges, agg,
                  blockIdx.x * kBM, kBE);
}

// ---------------------------------------------------------------------------
// Update layer (MFMA): block = 128 nodes; X row = [node(64)|agg(96)], K=160.
// ---------------------------------------------------------------------------
__global__ __launch_bounds__(512) void upd_mfma(
    const float* __restrict__ nodes, const float* __restrict__ agg,
    const short* __restrict__ wuT, const float* __restrict__ bu,
    const float* __restrict__ g, const float* __restrict__ be,
    float* __restrict__ out_upd) {
    __shared__ short sX[kBM * kLd];
    __shared__ short sB[96 * kLd];
    const int tid = threadIdx.x;
    if (tid < 256) {
        const int r = tid >> 1, half = tid & 1;
        const int node = blockIdx.x * kBM + r;
        const bool ok = node < kBN;
        short* dstRow = sX + r * kLd;
        const s16x8 z = {};
        if (half == 0) {
            const float4* p = reinterpret_cast<const float4*>(
                nodes + (size_t)(ok ? node : 0) * kF);
#pragma unroll
            for (int c = 0; c < 8; ++c)
                *reinterpret_cast<s16x8*>(dstRow + 8 * c) =
                    ok ? pack8(p[2 * c], p[2 * c + 1]) : z;
        } else {
            const float4* p = reinterpret_cast<const float4*>(
                agg + (size_t)(ok ? node : 0) * kFil);
#pragma unroll
            for (int c = 0; c < 12; ++c)
                *reinterpret_cast<s16x8*>(dstRow + 64 + 8 * c) =
                    ok ? pack8(p[2 * c], p[2 * c + 1]) : z;
        }
    } else {
        for (int i = tid - 256; i < 96 * kKp / 8; i += 256) {
            const int n = i / 20, c = i % 20;
            *reinterpret_cast<s16x8*>(sB + n * kLd + 8 * c) =
                *reinterpret_cast<const s16x8*>(wuT + n * kKp + 8 * c);
        }
    }
    __syncthreads();
    gemm_ln_store(sX, sB, bu, g, be, out_upd, nullptr, nullptr,
                  blockIdx.x * kBM, kBN);
}

extern "C" void kernel_launch(void* const* d_in, const int* in_sizes, int n_in,
                              void* d_out, int out_size, void* d_ws, size_t ws_size,
                              hipStream_t stream) {
    const float* nodes  = (const float*)d_in[0];
    const float* efeat  = (const float*)d_in[1];
    const int*   edges  = (const int*)d_in[2];
    const float* Wm     = (const float*)d_in[3];
    const float* bm     = (const float*)d_in[4];
    const float* ln_m_g = (const float*)d_in[5];
    const float* ln_m_b = (const float*)d_in[6];
    const float* Wu     = (const float*)d_in[7];
    const float* bu     = (const float*)d_in[8];
    const float* ln_u_g = (const float*)d_in[9];
    const float* ln_u_b = (const float*)d_in[10];

    float* out_upd = (float*)d_out;                           // (B,N,96) first
    float* out_msg = (float*)d_out + (size_t)kBN * kFil;      // (B,E,96) second

    // workspace layout (~15.4 MB); 16B-aligned segments
    short* wmT = (short*)d_ws;                                // 96*160 bf16
    short* wuT = wmT + 96 * kKp;                              // 96*160 bf16
    float* agg = (float*)(wuT + 96 * kKp);                    // B*N*96 floats

    // zero the aggregation buffer (atomic accumulation target)
    hipMemsetAsync(agg, 0, (size_t)kBN * kFil * sizeof(float), stream);
    prep_wT<<<(96 * kKp + 255) / 256, 256, 0, stream>>>(Wm, Wu, wmT, wuT);

    msg_mfma<<<kBE / kBM, 512, 0, stream>>>(
        nodes, efeat, edges, wmT, bm, ln_m_g, ln_m_b, out_msg, agg);
    upd_mfma<<<(kBN + kBM - 1) / kBM, 512, 0, stream>>>(
        nodes, agg, wuT, bu, ln_u_g, ln_u_b, out_upd);
}